// Round 3
// baseline (107.978 us; speedup 1.0000x reference)
//
#include <hip/hip_runtime.h>

// EPN layer: B=8, N=256, DH=32, DX=3, DQ=1, DE=8, H1=H2=32, DIN=80.
// layer1 = relu(Pa[i] + Pb'[j] + e_ij@W1e), Pb' has b1 folded in.
// b3 cancels in 0.5*(elec_ij - elec_ji).
//
// R1: remat. R3: fission. R5: AGPR accs. R6: MFMA layer-2, LDS Z (107.2us).
// R7-9: barrier-free k-split regressed. R10: LDS swizzle + global A-frags
//   regressed (bundled, barrier present). R11: ez f32x4 neutral ->
//   latency/occupancy-bound. R12: one-orientation E + transpose-read kernel C
//   (106.8) -- NOTE: used e[j,i] for ji orientation; its absmax 0.875 vs
//   threshold 0.975 was real math error, passed by luck. R13: barrier-free
//   wave-local MFMA tiles + global A-frags (105.7); top-5 dispatches were
//   256MB poison fills (~44us each) -> our kernels all < 43us.
// R14: collapse the pipeline. Both orientations share ez = e_ij@W1e, so
//   compute elec_ij AND elec_ji in one block, antisymmetrize + reduce
//   in-block -> antisym kernel + E/G workspace deleted (-4MB wr, -6MB rd,
//   -transpose gather, -1 dispatch). Exact per reference (ji uses e[i,j]).
//   FAILED: red[8]/8-wave sum, but block has 4 waves -> summed 4
//   uninitialized LDS slots (absmax 2701).
// R15: fix red[4]/4-wave sum. No other change (clean measurement of R14).

#define NATOM 256
#define TOT_ATOMS 2048
#define ZS 36   // ushort elems per Z row: 72 B, 18-bank stride -> 2-way max

typedef __bf16 bf16x8 __attribute__((ext_vector_type(8)));
typedef float  f32x16 __attribute__((ext_vector_type(16)));
typedef float  f32x4  __attribute__((ext_vector_type(4)));

__device__ __forceinline__ unsigned int pk2(float a, float b) {
    unsigned short lo = __builtin_bit_cast(unsigned short, (__bf16)a);
    unsigned short hi = __builtin_bit_cast(unsigned short, (__bf16)b);
    return (unsigned int)lo | ((unsigned int)hi << 16);
}

// ---- Kernel A: per-atom projections, P[atom][64]: c<32 = Pa, c>=32 = Pb+b1.
__global__ __launch_bounds__(256) void atom_proj_kernel(
    const float* __restrict__ x, const float* __restrict__ h,
    const float* __restrict__ q, const float* __restrict__ W1,
    const float* __restrict__ b1, float* __restrict__ P)
{
    const int a  = threadIdx.x >> 5;   // 0..7
    const int u  = threadIdx.x & 31;   // 0..31
    const int n0 = blockIdx.x * 8;

    __shared__ float sd[8][37];        // x(3), h(32), q(1), pad
    for (int idx = threadIdx.x; idx < 8 * 36; idx += 256) {
        const int aa = idx / 36, r = idx - aa * 36;
        const int n = n0 + aa;
        float v;
        if (r < 3)       v = x[n * 3 + r];
        else if (r < 35) v = h[n * 32 + (r - 3)];
        else             v = q[n];
        sd[aa][r] = v;
    }
    __syncthreads();

    float pa = 0.f, pb = b1[u];
#pragma unroll
    for (int r = 0; r < 36; ++r) {
        const float d = sd[a][r];
        pa += d * W1[r * 32 + u];
        pb += d * W1[(36 + r) * 32 + u];
    }
    const int n = n0 + a;
    P[(size_t)n * 64 + u]      = pa;
    P[(size_t)n * 64 + 32 + u] = pb;
}

// ---- Kernel B (fused): one block per (b,i) row. Computes BOTH orientations
//      per pair (shared ez), antisymmetrizes, gates, and reduces to
//      out[row] = q[row] + sum_j g*(dij - dji). No E/G globals.
__global__ __launch_bounds__(256, 4) void elec_fused_kernel(
    const float* __restrict__ e, const float* __restrict__ mask,
    const float* __restrict__ P, const float* __restrict__ W1,
    const float* __restrict__ W2, const float* __restrict__ b2,
    const float* __restrict__ W3, const float* __restrict__ q,
    float* __restrict__ out)
{
    const int row = blockIdx.x;          // b*256 + i == atom index of i
    const int b   = row >> 8;
    const int j   = threadIdx.x;
    const int col = (b << 8) + j;        // atom index of j

    __shared__ unsigned short Zij[256 * ZS];   // 18 KB, wave-disjoint rows
    __shared__ unsigned short Zji[256 * ZS];   // 18 KB
    __shared__ float Gs[256];                  // gate per column
    __shared__ float red[4];                   // one slot per wave (4 waves!)

    const int wave = threadIdx.x >> 6;
    const int lane = threadIdx.x & 63;
    const int lo = lane & 31;     // = u for A, = j-col for B/C
    const int h  = lane >> 5;     // k-half selector / C row offset

    // ---- per-pair scalars; gate -> LDS (wave-local consumption)
    const float* ep = e + (size_t)(row * NATOM + j) * 8;
    const float4 ev0 = ((const float4*)ep)[0];
    const float4 ev1 = ((const float4*)ep)[1];
    const float m = mask[row * NATOM + j];
    const float mx = fmaxf(fmaxf(fmaxf(ev0.x, ev0.y), fmaxf(ev0.z, ev0.w)),
                           fmaxf(fmaxf(ev1.x, ev1.y), fmaxf(ev1.z, ev1.w)));
    Gs[j] = (mx > 1e-5f) ? 0.5f * m : 0.f;

    // ---- layer 1, BOTH orientations, shared ez:
    //      z_ij = relu(Pa[i] + Pb[j] + ez),  z_ji = relu(Pa[j] + Pb[i] + ez)
    const float* Pi = P + (size_t)row * 64;   // uniform -> s_loads
    const float* Pj = P + (size_t)col * 64;   // per-thread vector loads
#pragma unroll
    for (int kq = 0; kq < 8; ++kq) {
        const float4 paj4 = ((const float4*)Pj)[kq];
        const float4 pbj4 = ((const float4*)Pj)[8 + kq];
        const int k0 = kq * 4;

        f32x4 ez = {0.f, 0.f, 0.f, 0.f};
        ez += (*(const f32x4*)(W1 + (72 + 0) * 32 + k0)) * ev0.x;
        ez += (*(const f32x4*)(W1 + (72 + 1) * 32 + k0)) * ev0.y;
        ez += (*(const f32x4*)(W1 + (72 + 2) * 32 + k0)) * ev0.z;
        ez += (*(const f32x4*)(W1 + (72 + 3) * 32 + k0)) * ev0.w;
        ez += (*(const f32x4*)(W1 + (72 + 4) * 32 + k0)) * ev1.x;
        ez += (*(const f32x4*)(W1 + (72 + 5) * 32 + k0)) * ev1.y;
        ez += (*(const f32x4*)(W1 + (72 + 6) * 32 + k0)) * ev1.z;
        ez += (*(const f32x4*)(W1 + (72 + 7) * 32 + k0)) * ev1.w;

        const float pai0 = Pi[k0 + 0], pai1 = Pi[k0 + 1];
        const float pai2 = Pi[k0 + 2], pai3 = Pi[k0 + 3];
        const float pbi0 = Pi[32 + k0 + 0], pbi1 = Pi[32 + k0 + 1];
        const float pbi2 = Pi[32 + k0 + 2], pbi3 = Pi[32 + k0 + 3];

        const float zij0 = fmaxf(pai0 + pbj4.x + ez[0], 0.f);
        const float zij1 = fmaxf(pai1 + pbj4.y + ez[1], 0.f);
        const float zij2 = fmaxf(pai2 + pbj4.z + ez[2], 0.f);
        const float zij3 = fmaxf(pai3 + pbj4.w + ez[3], 0.f);
        *(uint2*)&Zij[j * ZS + k0] = make_uint2(pk2(zij0, zij1), pk2(zij2, zij3));

        const float zji0 = fmaxf(paj4.x + pbi0 + ez[0], 0.f);
        const float zji1 = fmaxf(paj4.y + pbi1 + ez[1], 0.f);
        const float zji2 = fmaxf(paj4.z + pbi2 + ez[2], 0.f);
        const float zji3 = fmaxf(paj4.w + pbi3 + ez[3], 0.f);
        *(uint2*)&Zji[j * ZS + k0] = make_uint2(pk2(zji0, zji1), pk2(zji2, zji3));
    }

    // ---- A-frags direct from W2 (4 KB, L1-hot after first block on CU).
    bf16x8 a0, a1;
#pragma unroll
    for (int t = 0; t < 8; ++t) {
        a0[t] = (__bf16)W2[(h * 8 + t) * 32 + lo];
        a1[t] = (__bf16)W2[(16 + h * 8 + t) * 32 + lo];
    }

    // ---- layer 2 via MFMA, wave-local tiles (wave w consumes exactly the
    //      Z rows [w*64, w*64+64) its own lanes wrote -> no barrier needed;
    //      in-wave LDS RAW ordering enforced by compiler lgkmcnt).
    float vacc = 0.f;
#pragma unroll
    for (int nt = 0; nt < 2; ++nt) {
        const int jt = wave * 64 + nt * 32;      // wave-local j-tile base
        const int zo = (jt + lo) * ZS + h * 8;

        f32x16 cij = {0.f};
        {
            const bf16x8 bz0 = *(const bf16x8*)&Zij[zo];
            const bf16x8 bz1 = *(const bf16x8*)&Zij[zo + 16];
            cij = __builtin_amdgcn_mfma_f32_32x32x16_bf16(a0, bz0, cij, 0, 0, 0);
            cij = __builtin_amdgcn_mfma_f32_32x32x16_bf16(a1, bz1, cij, 0, 0, 0);
        }
        f32x16 cji = {0.f};
        {
            const bf16x8 bz0 = *(const bf16x8*)&Zji[zo];
            const bf16x8 bz1 = *(const bf16x8*)&Zji[zo + 16];
            cji = __builtin_amdgcn_mfma_f32_32x32x16_bf16(a0, bz0, cji, 0, 0, 0);
            cji = __builtin_amdgcn_mfma_f32_32x32x16_bf16(a1, bz1, cji, 0, 0, 0);
        }

        // layer 3 for both: d = sum_u relu(C[u][j'] + b2[u]) * W3[u]
        // C row u = (reg&3) + 8*(reg>>2) + 4*h -> float4 b2/W3 loads.
        float dij = 0.f, dji = 0.f;
#pragma unroll
        for (int rq = 0; rq < 4; ++rq) {
            const int u0 = 8 * rq + 4 * h;
            const float4 b2v = *(const float4*)&b2[u0];
            const float4 w3v = *(const float4*)&W3[u0];
            dij += fmaxf(cij[4 * rq + 0] + b2v.x, 0.f) * w3v.x;
            dij += fmaxf(cij[4 * rq + 1] + b2v.y, 0.f) * w3v.y;
            dij += fmaxf(cij[4 * rq + 2] + b2v.z, 0.f) * w3v.z;
            dij += fmaxf(cij[4 * rq + 3] + b2v.w, 0.f) * w3v.w;
            dji += fmaxf(cji[4 * rq + 0] + b2v.x, 0.f) * w3v.x;
            dji += fmaxf(cji[4 * rq + 1] + b2v.y, 0.f) * w3v.y;
            dji += fmaxf(cji[4 * rq + 2] + b2v.z, 0.f) * w3v.z;
            dji += fmaxf(cji[4 * rq + 3] + b2v.w, 0.f) * w3v.w;
        }
        dij += __shfl_xor(dij, 32, 64);          // full 32-u sum in both halves
        dji += __shfl_xor(dji, 32, 64);

        if (h == 0)
            vacc += Gs[jt + lo] * (dij - dji);   // antisym, gated
    }

    // ---- block reduction -> out[row] = q[row] + sum_j g*(dij - dji)
#pragma unroll
    for (int off = 1; off < 64; off <<= 1)
        vacc += __shfl_xor(vacc, off, 64);
    if (lane == 0) red[wave] = vacc;
    __syncthreads();
    if (threadIdx.x == 0)
        out[row] = q[row] + (red[0] + red[1] + red[2] + red[3]);
}

extern "C" void kernel_launch(void* const* d_in, const int* in_sizes, int n_in,
                              void* d_out, int out_size, void* d_ws, size_t ws_size,
                              hipStream_t stream)
{
    const float* h    = (const float*)d_in[0];
    const float* e    = (const float*)d_in[1];
    const float* x    = (const float*)d_in[2];
    const float* q    = (const float*)d_in[3];
    const float* mask = (const float*)d_in[4];
    const float* W1   = (const float*)d_in[5];
    const float* b1   = (const float*)d_in[6];
    const float* W2   = (const float*)d_in[7];
    const float* b2   = (const float*)d_in[8];
    const float* W3   = (const float*)d_in[9];
    // b3 cancels in the antisymmetric difference.

    float* P = (float*)d_ws;            // [2048][64] = 512 KB (only ws use)

    atom_proj_kernel<<<256, 256, 0, stream>>>(x, h, q, W1, b1, P);
    elec_fused_kernel<<<TOT_ATOMS, 256, 0, stream>>>(e, mask, P, W1, W2, b2,
                                                     W3, q, (float*)d_out);
}